// Round 19
// baseline (264.584 us; speedup 1.0000x reference)
//
#include <hip/hip_runtime.h>
#include <hip/hip_bf16.h>

#define NTOK 49
#define QSC 0.1767766952966369f
#define LOG2E 1.4426950408889634f

typedef __attribute__((ext_vector_type(8))) short short8;
typedef __attribute__((ext_vector_type(4))) float f32x4;

__device__ __forceinline__ unsigned short f2bf(float f) {
  union { float f; unsigned u; } v; v.f = f;
  unsigned r = v.u + 0x7FFFu + ((v.u >> 16) & 1u);  // round-to-nearest-even
  return (unsigned short)(r >> 16);
}

// packed f32x2 -> bf16x2 (v_cvt_pk_bf16_f32), RNE; low word = a
__device__ __forceinline__ unsigned pk2bf(float a, float b) {
  __hip_bfloat162 h = __float22bfloat162_rn(float2{a, b});
  union { __hip_bfloat162 h; unsigned u; } c; c.h = h;
  return c.u;
}

// ---- swizzled LDS index helper (shorts; granule = 16B = 8 shorts). WRITE sites only ----
__device__ __forceinline__ int vp_ix(int row, int col) {
  int gi = (col >> 3) ^ (row & 7);
  return row * 64 + (gi << 3) + (col & 7);
}

// ---------------- prep 1: Q/K weight swizzle (Q pre-scaled by QSC*log2e) + bias+mask (log2 domain) ----------------
__global__ void prep_kernel(const float* __restrict__ qkv_w,
                            const float* __restrict__ bias_table,
                            const int* __restrict__ rel_index,
                            const float* __restrict__ mask,
                            unsigned short* __restrict__ w_swz,
                            float* __restrict__ bm3, int nW)
{
  int idx = blockIdx.x * 256 + threadIdx.x;
  if (idx < 165888) {
    int f = idx >> 9, r = idx & 511;
    int l = r >> 3, j = r & 7;
    int nt = f / 9, ks = f - nt * 9;
    int row = nt * 16 + (l & 15);
    int k = ks * 32 + ((l >> 4) << 3) + j;
    float wv = qkv_w[row * 288 + k];
    if (nt < 18) wv *= QSC * LOG2E;       // fold softmax scale + exp2 domain into Q weights
    w_swz[idx] = f2bf(wv);
  } else {
    int t = idx - 165888;
    if (t < 3 * 64 * 49 * 64) {
      int h = t / (64 * 49 * 64);
      int r = t - h * (64 * 49 * 64);
      int wi = r / (49 * 64);
      int rem = r - wi * (49 * 64);
      int n = rem >> 6, m = rem & 63;
      float v = -1e30f;
      if (m < NTOK)
        v = LOG2E * (bias_table[rel_index[n * 49 + m] * 3 + h] + mask[(size_t)wi * 2401 + n * 49 + m]);
      bm3[t] = v;
    }
  }
}

// ---------------- prep 2: fold proj into V:  WVP_h = P_h @ Wv_h  (fp32), swizzled bf16 ----------------
__global__ void prep2_kernel(const float* __restrict__ qkv_w,
                             const float* __restrict__ qkv_b,
                             const float* __restrict__ proj_w,
                             const float* __restrict__ proj_b,
                             unsigned short* __restrict__ w_swz,
                             float* __restrict__ cb)
{
  int idx = blockIdx.x * 256 + threadIdx.x;
  if (idx < 82944) {
    int f = idx >> 9, r = idx & 511;
    int l = r >> 3, j = r & 7;
    int hn = f / 9, ks = f - hn * 9;
    int h = hn / 6, ntd = hn - h * 6;
    int d = ntd * 16 + (l & 15);
    int k = ks * 32 + ((l >> 4) << 3) + j;
    const float* pr = proj_w + d * 288 + h * 96;
    const float* wr = qkv_w + (size_t)(576 + h * 96) * 288 + k;
    float s = 0.f;
    #pragma unroll 8
    for (int t = 0; t < 96; ++t) s += pr[t] * wr[(size_t)t * 288];
    w_swz[165888 + idx] = f2bf(s);
  } else if (idx < 82944 + 96) {
    int d = idx - 82944;
    float s = proj_b[d];
    #pragma unroll 1
    for (int h = 0; h < 3; ++h) {
      const float* pr = proj_w + d * 288 + h * 96;
      const float* bv = qkv_b + 576 + h * 96;
      #pragma unroll 8
      for (int t = 0; t < 96; ++t) s += pr[t] * bv[t];
    }
    cb[d] = s;
  }
}

// ---------------- fused window attention, 8 waves, swizzled LDS, proj folded ----------------
#define A_OFF 0
#define Q_OFF 18432
#define K_OFF 23136
#define VT_OFF 27840
#define P_OFF 33984
#define SMEM_TOT 38080   // 76160 bytes -> 2 blocks/CU

__global__ __launch_bounds__(512, 4)
void wattn_kernel(const float* __restrict__ x, const float* __restrict__ y,
                  const float* __restrict__ z,
                  const float* __restrict__ qkv_b, const float* __restrict__ cb,
                  const unsigned short* __restrict__ w_swz,
                  const float* __restrict__ bm3,
                  float* __restrict__ out, int nW)
{
  __shared__ unsigned short smem[SMEM_TOT];
  const int b = blockIdx.x;
  const int tid = threadIdx.x;
  const int w = tid >> 6;        // 0..7
  const int lane = tid & 63;
  const int g = lane >> 4;
  const int cl = lane & 15;
  const int widx = b % nW;
  const int t4 = w & 3;          // row-tile for S/PV
  const int hf = w >> 2;         // half split

  // per-thread affine swizzle constants (reads)
  const int gx = ((g ^ ((cl >> 1) & 3)) << 3);   // A/Q/K granule adj (shorts)
  const int c2 = (cl >> 2) & 1;
  const int gv = ((g ^ (cl & 3)) << 3);          // Vt/P granule adj (shorts)
  const int s0 = c2 << 5;                        // Vt/P ks=0 offset (shorts)
  const int s1 = 32 - s0;                        // Vt/P ks=1 offset

  // ---- stage concat(x,y,z) -> LDS bf16, swizzled; all 9 loads in flight ----
  {
    const int row = tid >> 3;
    const int t7 = tid & 7;
    const int lb = row * 288 + (((t7 >> 1) ^ ((row >> 1) & 3)) << 3) + (t7 & 1) * 4;
    const size_t gb = ((size_t)b * NTOK + row) * 96 + t7 * 4;
    float4 v[9];
    if (row < NTOK) {
      #pragma unroll
      for (int k3 = 0; k3 < 3; ++k3) {
        v[0 + k3] = *(const float4*)(x + gb + k3 * 32);
        v[3 + k3] = *(const float4*)(y + gb + k3 * 32);
        v[6 + k3] = *(const float4*)(z + gb + k3 * 32);
      }
    } else {
      #pragma unroll
      for (int i = 0; i < 9; ++i) v[i] = make_float4(0.f, 0.f, 0.f, 0.f);
    }
    #pragma unroll
    for (int i = 0; i < 9; ++i) {
      uint2 d;
      d.x = pk2bf(v[i].x, v[i].y);
      d.y = pk2bf(v[i].z, v[i].w);
      *(uint2*)&smem[lb + (i / 3) * 96 + (i % 3) * 32] = d;
    }
  }

  // QKV pass-1 tile constants (tiles 0..15): wave owns 2w, 2w+1 (same type s per wave)
  const int tA = 2 * w;
  const int sA = (tA >= 12) ? 2 : ((tA >= 6) ? 1 : 0);
  const int dA = tA - 6 * sA, dB = dA + 1;
  // merged V'-chain: tiles 16,17 split by m-tile across 8 waves
  const int mw = w & 3;
  const int d2t = 4 + (w >> 2);

  f32x4 outacc[3];
  #pragma unroll
  for (int i = 0; i < 3; ++i) outacc[i] = f32x4{0.f, 0.f, 0.f, 0.f};

  __syncthreads();

  #pragma unroll 1
  for (int h = 0; h < 3; ++h) {
    __syncthreads();

    // ---- QKV: two tiles per wave, SEQUENTIAL; V'-chain merged into tile-A loop ----
    {
      const unsigned short* abase = &smem[A_OFF + cl * 288 + gx];
      const unsigned short* abm   = &smem[A_OFF + (mw * 16 + cl) * 288 + gx];
      const unsigned short* wpC   = w_swz + (size_t)(36 + h * 6 + d2t) * 9 * 512 + lane * 8;
      f32x4 acc2 = f32x4{0.f, 0.f, 0.f, 0.f};

      if (sA == 2) {
        // V' waves: D rows=tokens, packed Vt writeback
        #pragma unroll 1
        for (int t = 0; t < 2; ++t) {
          const int ntd = t ? dB : dA;
          const unsigned short* wp = w_swz + (size_t)(2 * 18 + h * 6 + ntd) * 9 * 512 + lane * 8;
          f32x4 acc[4];
          #pragma unroll
          for (int m = 0; m < 4; ++m) acc[m] = f32x4{0.f, 0.f, 0.f, 0.f};
          short8 bf = *(const short8*)(wp);
          short8 cw = *(const short8*)(wpC);
          if (t == 0) {
            #pragma unroll 4
            for (int ks = 0; ks < 8; ++ks) {
              short8 bfn = *(const short8*)(wp + (ks + 1) * 512);
              short8 cwn = *(const short8*)(wpC + (ks + 1) * 512);
              short8 af0 = *(const short8*)(abase + 0 * (16 * 288) + ks * 32);
              short8 af1 = *(const short8*)(abase + 1 * (16 * 288) + ks * 32);
              short8 af2 = *(const short8*)(abase + 2 * (16 * 288) + ks * 32);
              short8 af3 = *(const short8*)(abase + 3 * (16 * 288) + ks * 32);
              short8 afm = *(const short8*)(abm + ks * 32);
              __builtin_amdgcn_s_setprio(1);
              acc[0] = __builtin_amdgcn_mfma_f32_16x16x32_bf16(af0, bf, acc[0], 0, 0, 0);
              acc[1] = __builtin_amdgcn_mfma_f32_16x16x32_bf16(af1, bf, acc[1], 0, 0, 0);
              acc[2] = __builtin_amdgcn_mfma_f32_16x16x32_bf16(af2, bf, acc[2], 0, 0, 0);
              acc[3] = __builtin_amdgcn_mfma_f32_16x16x32_bf16(af3, bf, acc[3], 0, 0, 0);
              acc2   = __builtin_amdgcn_mfma_f32_16x16x32_bf16(afm, cw, acc2, 0, 0, 0);
              __builtin_amdgcn_s_setprio(0);
              bf = bfn; cw = cwn;
            }
            short8 af0 = *(const short8*)(abase + 0 * (16 * 288) + 8 * 32);
            short8 af1 = *(const short8*)(abase + 1 * (16 * 288) + 8 * 32);
            short8 af2 = *(const short8*)(abase + 2 * (16 * 288) + 8 * 32);
            short8 af3 = *(const short8*)(abase + 3 * (16 * 288) + 8 * 32);
            short8 afm = *(const short8*)(abm + 8 * 32);
            __builtin_amdgcn_s_setprio(1);
            acc[0] = __builtin_amdgcn_mfma_f32_16x16x32_bf16(af0, bf, acc[0], 0, 0, 0);
            acc[1] = __builtin_amdgcn_mfma_f32_16x16x32_bf16(af1, bf, acc[1], 0, 0, 0);
            acc[2] = __builtin_amdgcn_mfma_f32_16x16x32_bf16(af2, bf, acc[2], 0, 0, 0);
            acc[3] = __builtin_amdgcn_mfma_f32_16x16x32_bf16(af3, bf, acc[3], 0, 0, 0);
            acc2   = __builtin_amdgcn_mfma_f32_16x16x32_bf16(afm, cw, acc2, 0, 0, 0);
            __builtin_amdgcn_s_setprio(0);
          } else {
            #pragma unroll 4
            for (int ks = 0; ks < 8; ++ks) {
              short8 bfn = *(const short8*)(wp + (ks + 1) * 512);
              short8 af0 = *(const short8*)(abase + 0 * (16 * 288) + ks * 32);
              short8 af1 = *(const short8*)(abase + 1 * (16 * 288) + ks * 32);
              short8 af2 = *(const short8*)(abase + 2 * (16 * 288) + ks * 32);
              short8 af3 = *(const short8*)(abase + 3 * (16 * 288) + ks * 32);
              __builtin_amdgcn_s_setprio(1);
              acc[0] = __builtin_amdgcn_mfma_f32_16x16x32_bf16(af0, bf, acc[0], 0, 0, 0);
              acc[1] = __builtin_amdgcn_mfma_f32_16x16x32_bf16(af1, bf, acc[1], 0, 0, 0);
              acc[2] = __builtin_amdgcn_mfma_f32_16x16x32_bf16(af2, bf, acc[2], 0, 0, 0);
              acc[3] = __builtin_amdgcn_mfma_f32_16x16x32_bf16(af3, bf, acc[3], 0, 0, 0);
              __builtin_amdgcn_s_setprio(0);
              bf = bfn;
            }
            short8 af0 = *(const short8*)(abase + 0 * (16 * 288) + 8 * 32);
            short8 af1 = *(const short8*)(abase + 1 * (16 * 288) + 8 * 32);
            short8 af2 = *(const short8*)(abase + 2 * (16 * 288) + 8 * 32);
            short8 af3 = *(const short8*)(abase + 3 * (16 * 288) + 8 * 32);
            __builtin_amdgcn_s_setprio(1);
            acc[0] = __builtin_amdgcn_mfma_f32_16x16x32_bf16(af0, bf, acc[0], 0, 0, 0);
            acc[1] = __builtin_amdgcn_mfma_f32_16x16x32_bf16(af1, bf, acc[1], 0, 0, 0);
            acc[2] = __builtin_amdgcn_mfma_f32_16x16x32_bf16(af2, bf, acc[2], 0, 0, 0);
            acc[3] = __builtin_amdgcn_mfma_f32_16x16x32_bf16(af3, bf, acc[3], 0, 0, 0);
            __builtin_amdgcn_s_setprio(0);
          }
          #pragma unroll
          for (int m = 0; m < 4; ++m) {
            uint2 d;
            d.x = pk2bf(acc[m][0], acc[m][1]);
            d.y = pk2bf(acc[m][2], acc[m][3]);
            *(uint2*)&smem[VT_OFF + vp_ix(ntd * 16 + cl, m * 16 + (g << 2))] = d;
          }
        }
      } else {
        // Q/K waves: SWAPPED (D rows=d, cols=tokens), packed writeback, scale pre-folded
        const int s = sA;
        const int off = s ? K_OFF : Q_OFF;
        const float bsc = s ? 1.f : (QSC * LOG2E);
        #pragma unroll 1
        for (int t = 0; t < 2; ++t) {
          const int ntd = t ? dB : dA;
          const unsigned short* wp = w_swz + (size_t)(s * 18 + h * 6 + ntd) * 9 * 512 + lane * 8;
          f32x4 acc[4];
          #pragma unroll
          for (int m = 0; m < 4; ++m) acc[m] = f32x4{0.f, 0.f, 0.f, 0.f};
          short8 bf = *(const short8*)(wp);
          short8 cw = *(const short8*)(wpC);
          if (t == 0) {
            #pragma unroll 4
            for (int ks = 0; ks < 8; ++ks) {
              short8 bfn = *(const short8*)(wp + (ks + 1) * 512);
              short8 cwn = *(const short8*)(wpC + (ks + 1) * 512);
              short8 af0 = *(const short8*)(abase + 0 * (16 * 288) + ks * 32);
              short8 af1 = *(const short8*)(abase + 1 * (16 * 288) + ks * 32);
              short8 af2 = *(const short8*)(abase + 2 * (16 * 288) + ks * 32);
              short8 af3 = *(const short8*)(abase + 3 * (16 * 288) + ks * 32);
              short8 afm = *(const short8*)(abm + ks * 32);
              __builtin_amdgcn_s_setprio(1);
              acc[0] = __builtin_amdgcn_mfma_f32_16x16x32_bf16(bf, af0, acc[0], 0, 0, 0);
              acc[1] = __builtin_amdgcn_mfma_f32_16x16x32_bf16(bf, af1, acc[1], 0, 0, 0);
              acc[2] = __builtin_amdgcn_mfma_f32_16x16x32_bf16(bf, af2, acc[2], 0, 0, 0);
              acc[3] = __builtin_amdgcn_mfma_f32_16x16x32_bf16(bf, af3, acc[3], 0, 0, 0);
              acc2   = __builtin_amdgcn_mfma_f32_16x16x32_bf16(afm, cw, acc2, 0, 0, 0);
              __builtin_amdgcn_s_setprio(0);
              bf = bfn; cw = cwn;
            }
            short8 af0 = *(const short8*)(abase + 0 * (16 * 288) + 8 * 32);
            short8 af1 = *(const short8*)(abase + 1 * (16 * 288) + 8 * 32);
            short8 af2 = *(const short8*)(abase + 2 * (16 * 288) + 8 * 32);
            short8 af3 = *(const short8*)(abase + 3 * (16 * 288) + 8 * 32);
            short8 afm = *(const short8*)(abm + 8 * 32);
            __builtin_amdgcn_s_setprio(1);
            acc[0] = __builtin_amdgcn_mfma_f32_16x16x32_bf16(bf, af0, acc[0], 0, 0, 0);
            acc[1] = __builtin_amdgcn_mfma_f32_16x16x32_bf16(bf, af1, acc[1], 0, 0, 0);
            acc[2] = __builtin_amdgcn_mfma_f32_16x16x32_bf16(bf, af2, acc[2], 0, 0, 0);
            acc[3] = __builtin_amdgcn_mfma_f32_16x16x32_bf16(bf, af3, acc[3], 0, 0, 0);
            acc2   = __builtin_amdgcn_mfma_f32_16x16x32_bf16(afm, cw, acc2, 0, 0, 0);
            __builtin_amdgcn_s_setprio(0);
          } else {
            #pragma unroll 4
            for (int ks = 0; ks < 8; ++ks) {
              short8 bfn = *(const short8*)(wp + (ks + 1) * 512);
              short8 af0 = *(const short8*)(abase + 0 * (16 * 288) + ks * 32);
              short8 af1 = *(const short8*)(abase + 1 * (16 * 288) + ks * 32);
              short8 af2 = *(const short8*)(abase + 2 * (16 * 288) + ks * 32);
              short8 af3 = *(const short8*)(abase + 3 * (16 * 288) + ks * 32);
              __builtin_amdgcn_s_setprio(1);
              acc[0] = __builtin_amdgcn_mfma_f32_16x16x32_bf16(bf, af0, acc[0], 0, 0, 0);
              acc[1] = __builtin_amdgcn_mfma_f32_16x16x32_bf16(bf, af1, acc[1], 0, 0, 0);
              acc[2] = __builtin_amdgcn_mfma_f32_16x16x32_bf16(bf, af2, acc[2], 0, 0, 0);
              acc[3] = __builtin_amdgcn_mfma_f32_16x16x32_bf16(bf, af3, acc[3], 0, 0, 0);
              __builtin_amdgcn_s_setprio(0);
              bf = bfn;
            }
            short8 af0 = *(const short8*)(abase + 0 * (16 * 288) + 8 * 32);
            short8 af1 = *(const short8*)(abase + 1 * (16 * 288) + 8 * 32);
            short8 af2 = *(const short8*)(abase + 2 * (16 * 288) + 8 * 32);
            short8 af3 = *(const short8*)(abase + 3 * (16 * 288) + 8 * 32);
            __builtin_amdgcn_s_setprio(1);
            acc[0] = __builtin_amdgcn_mfma_f32_16x16x32_bf16(bf, af0, acc[0], 0, 0, 0);
            acc[1] = __builtin_amdgcn_mfma_f32_16x16x32_bf16(bf, af1, acc[1], 0, 0, 0);
            acc[2] = __builtin_amdgcn_mfma_f32_16x16x32_bf16(bf, af2, acc[2], 0, 0, 0);
            acc[3] = __builtin_amdgcn_mfma_f32_16x16x32_bf16(bf, af3, acc[3], 0, 0, 0);
            __builtin_amdgcn_s_setprio(0);
          }
          const int d0 = ntd * 16 + (g << 2);
          float4 bq4 = *(const float4*)&qkv_b[s * 288 + h * 96 + d0];
          bq4.x *= bsc; bq4.y *= bsc; bq4.z *= bsc; bq4.w *= bsc;
          #pragma unroll
          for (int m = 0; m < 4; ++m) {
            int token = m * 16 + cl;
            uint2 dd;
            dd.x = pk2bf(acc[m][0] + bq4.x, acc[m][1] + bq4.y);
            dd.y = pk2bf(acc[m][2] + bq4.z, acc[m][3] + bq4.w);
            if (token < NTOK) {
              int gi = (d0 >> 3) ^ ((token >> 1) & 3);
              *(uint2*)&smem[off + token * 96 + (gi << 3) + (d0 & 7)] = dd;
            }
          }
        }
      }

      // merged V'-chain writeback (tiles 16,17)
      {
        uint2 d;
        d.x = pk2bf(acc2[0], acc2[1]);
        d.y = pk2bf(acc2[2], acc2[3]);
        *(uint2*)&smem[VT_OFF + vp_ix(d2t * 16 + cl, mw * 16 + (g << 2))] = d;
      }
    }
    __syncthreads();

    // ---- prefetch combined bias+mask (padded stride 64, log2 domain) ----
    float bm[2][4];
    {
      const float* bmb = bm3 + ((size_t)(h * nW + widx)) * (49 * 64) + cl;
      #pragma unroll
      for (int rr = 0; rr < 2; ++rr) {
        int n = t4 * 16 + (g << 2) + 2 * hf + rr;
        int nn = n < NTOK ? n : NTOK - 1;
        const float* brow = bmb + nn * 64;
        #pragma unroll
        for (int nt = 0; nt < 4; ++nt) bm[rr][nt] = brow[nt * 16];
      }
    }

    // ---- S = Q K^T (wave-pair duplicates its row-tile) ----
    f32x4 sacc[4];
    #pragma unroll
    for (int nt = 0; nt < 4; ++nt) sacc[nt] = f32x4{0.f, 0.f, 0.f, 0.f};
    {
      const unsigned short* qbase = &smem[Q_OFF + (t4 * 16 + cl) * 96 + gx];
      const unsigned short* kbase = &smem[K_OFF + cl * 96 + gx];
      #pragma unroll 1
      for (int ks = 0; ks < 3; ++ks) {
        short8 aq = *(const short8*)(qbase + ks * 32);
        short8 bk0 = *(const short8*)(kbase + 0 * (16 * 96) + ks * 32);
        short8 bk1 = *(const short8*)(kbase + 1 * (16 * 96) + ks * 32);
        short8 bk2 = *(const short8*)(kbase + 2 * (16 * 96) + ks * 32);
        short8 bk3 = *(const short8*)(kbase + 3 * (16 * 96) + ks * 32);
        __builtin_amdgcn_s_setprio(1);
        sacc[0] = __builtin_amdgcn_mfma_f32_16x16x32_bf16(aq, bk0, sacc[0], 0, 0, 0);
        sacc[1] = __builtin_amdgcn_mfma_f32_16x16x32_bf16(aq, bk1, sacc[1], 0, 0, 0);
        sacc[2] = __builtin_amdgcn_mfma_f32_16x16x32_bf16(aq, bk2, sacc[2], 0, 0, 0);
        sacc[3] = __builtin_amdgcn_mfma_f32_16x16x32_bf16(aq, bk3, sacc[3], 0, 0, 0);
        __builtin_amdgcn_s_setprio(0);
      }
    }

    // ---- softmax (log2 domain): wave handles rows r in {2hf, 2hf+1} ----
    #pragma unroll
    for (int r = 0; r < 4; ++r) {
      if ((r >> 1) != hf) continue;     // uniform; r compile-time
      const int rr = r & 1;
      int n = t4 * 16 + (g << 2) + r;
      float vals[4];
      #pragma unroll
      for (int nt = 0; nt < 4; ++nt) vals[nt] = sacc[nt][r] + bm[rr][nt];
      float mx = fmaxf(fmaxf(vals[0], vals[1]), fmaxf(vals[2], vals[3]));
      mx = fmaxf(mx, __shfl_xor(mx, 1));
      mx = fmaxf(mx, __shfl_xor(mx, 2));
      mx = fmaxf(mx, __shfl_xor(mx, 4));
      mx = fmaxf(mx, __shfl_xor(mx, 8));
      float sum = 0.f;
      #pragma unroll
      for (int nt = 0; nt < 4; ++nt) {
        float e = __builtin_amdgcn_exp2f(vals[nt] - mx);
        vals[nt] = e;
        sum += e;
      }
      sum += __shfl_xor(sum, 1);
      sum += __shfl_xor(sum, 2);
      sum += __shfl_xor(sum, 4);
      sum += __shfl_xor(sum, 8);
      float inv = __builtin_amdgcn_rcpf(sum);
      unsigned d01 = pk2bf(vals[0] * inv, vals[1] * inv);
      unsigned d23 = pk2bf(vals[2] * inv, vals[3] * inv);
      smem[P_OFF + vp_ix(n, 0 * 16 + cl)] = (unsigned short)d01;
      smem[P_OFF + vp_ix(n, 1 * 16 + cl)] = (unsigned short)(d01 >> 16);
      smem[P_OFF + vp_ix(n, 2 * 16 + cl)] = (unsigned short)d23;
      smem[P_OFF + vp_ix(n, 3 * 16 + cl)] = (unsigned short)(d23 >> 16);
    }
    __syncthreads();

    // ---- out partial: outacc += (P @ V') SWAPPED -> D rows=d, cols=tokens ----
    {
      const unsigned short* pbase = &smem[P_OFF + (t4 * 16 + cl) * 64 + gv];
      const unsigned short* vbase = &smem[VT_OFF + (hf * 3 * 16 + cl) * 64 + gv];
      #pragma unroll
      for (int ks = 0; ks < 2; ++ks) {
        const int ko = ks ? s1 : s0;
        short8 ap = *(const short8*)(pbase + ko);
        short8 bv0 = *(const short8*)(vbase + 0 * (16 * 64) + ko);
        short8 bv1 = *(const short8*)(vbase + 1 * (16 * 64) + ko);
        short8 bv2 = *(const short8*)(vbase + 2 * (16 * 64) + ko);
        __builtin_amdgcn_s_setprio(1);
        outacc[0] = __builtin_amdgcn_mfma_f32_16x16x32_bf16(bv0, ap, outacc[0], 0, 0, 0);
        outacc[1] = __builtin_amdgcn_mfma_f32_16x16x32_bf16(bv1, ap, outacc[1], 0, 0, 0);
        outacc[2] = __builtin_amdgcn_mfma_f32_16x16x32_bf16(bv2, ap, outacc[2], 0, 0, 0);
        __builtin_amdgcn_s_setprio(0);
      }
    }
  }

  // ---- epilogue: thread holds d = (hf*3+jj)*16+g*4+r at token n = t4*16+cl ----
  {
    int n = t4 * 16 + cl;
    if (n < NTOK) {
      size_t ob = ((size_t)b * NTOK + n) * 96;
      #pragma unroll
      for (int jj = 0; jj < 3; ++jj) {
        int d0 = (hf * 3 + jj) * 16 + (g << 2);
        float4 c4 = *(const float4*)&cb[d0];
        float4 o;
        o.x = outacc[jj][0] + c4.x;
        o.y = outacc[jj][1] + c4.y;
        o.z = outacc[jj][2] + c4.z;
        o.w = outacc[jj][3] + c4.w;
        *(float4*)&out[ob + d0] = o;
      }
    }
  }
}

extern "C" void kernel_launch(void* const* d_in, const int* in_sizes, int n_in,
                              void* d_out, int out_size, void* d_ws, size_t ws_size,
                              hipStream_t stream) {
  const float* x          = (const float*)d_in[0];
  const float* y          = (const float*)d_in[1];
  const float* z          = (const float*)d_in[2];
  const float* mask       = (const float*)d_in[3];
  const float* qkv_w      = (const float*)d_in[4];
  const float* qkv_b      = (const float*)d_in[5];
  const float* proj_w     = (const float*)d_in[6];
  const float* proj_b     = (const float*)d_in[7];
  const float* bias_table = (const float*)d_in[8];
  const int*   rel_index  = (const int*)d_in[9];

  int B  = in_sizes[0] / (NTOK * 96);
  int nW = in_sizes[3] / (NTOK * NTOK);

  unsigned short* w_swz = (unsigned short*)d_ws;        // 248832 shorts (54 tiles)
  float*          bm3   = (float*)(w_swz + 248832);     // 3*nW*49*64 floats
  float*          cbv   = bm3 + (size_t)3 * nW * 49 * 64;  // 96 floats

  int prep1_elems = 165888 + 3 * nW * 49 * 64;
  prep_kernel<<<(prep1_elems + 255) / 256, 256, 0, stream>>>(
      qkv_w, bias_table, rel_index, mask, w_swz, bm3, nW);
  prep2_kernel<<<325, 256, 0, stream>>>(qkv_w, qkv_b, proj_w, proj_b, w_swz, cbv);
  wattn_kernel<<<B, 512, 0, stream>>>(x, y, z, qkv_b, cbv,
                                      w_swz, bm3, (float*)d_out, nW);
}

// Round 20
// 232.022 us; speedup vs baseline: 1.1403x; 1.1403x over previous
//
#include <hip/hip_runtime.h>
#include <hip/hip_bf16.h>

#define NTOK 49
#define QSC 0.1767766952966369f
#define LOG2E 1.4426950408889634f

typedef __attribute__((ext_vector_type(8))) short short8;
typedef __attribute__((ext_vector_type(4))) float f32x4;

__device__ __forceinline__ unsigned short f2bf(float f) {
  union { float f; unsigned u; } v; v.f = f;
  unsigned r = v.u + 0x7FFFu + ((v.u >> 16) & 1u);  // round-to-nearest-even
  return (unsigned short)(r >> 16);
}

// packed f32x2 -> bf16x2 (v_cvt_pk_bf16_f32), RNE; low word = a
__device__ __forceinline__ unsigned pk2bf(float a, float b) {
  __hip_bfloat162 h = __float22bfloat162_rn(float2{a, b});
  union { __hip_bfloat162 h; unsigned u; } c; c.h = h;
  return c.u;
}

// ---- swizzled LDS index helper (shorts; granule = 16B = 8 shorts). WRITE sites only ----
__device__ __forceinline__ int vp_ix(int row, int col) {
  int gi = (col >> 3) ^ (row & 7);
  return row * 64 + (gi << 3) + (col & 7);
}

// ---------------- prep 1: Q/K weight swizzle (Q pre-scaled by QSC*log2e) + bias+mask (log2 domain) ----------------
__global__ void prep_kernel(const float* __restrict__ qkv_w,
                            const float* __restrict__ bias_table,
                            const int* __restrict__ rel_index,
                            const float* __restrict__ mask,
                            unsigned short* __restrict__ w_swz,
                            float* __restrict__ bm3, int nW)
{
  int idx = blockIdx.x * 256 + threadIdx.x;
  if (idx < 165888) {
    int f = idx >> 9, r = idx & 511;
    int l = r >> 3, j = r & 7;
    int nt = f / 9, ks = f - nt * 9;
    int row = nt * 16 + (l & 15);
    int k = ks * 32 + ((l >> 4) << 3) + j;
    float wv = qkv_w[row * 288 + k];
    if (nt < 18) wv *= QSC * LOG2E;       // fold softmax scale + exp2 domain into Q weights
    w_swz[idx] = f2bf(wv);
  } else {
    int t = idx - 165888;
    if (t < 3 * 64 * 49 * 64) {
      int h = t / (64 * 49 * 64);
      int r = t - h * (64 * 49 * 64);
      int wi = r / (49 * 64);
      int rem = r - wi * (49 * 64);
      int n = rem >> 6, m = rem & 63;
      float v = -1e30f;
      if (m < NTOK)
        v = LOG2E * (bias_table[rel_index[n * 49 + m] * 3 + h] + mask[(size_t)wi * 2401 + n * 49 + m]);
      bm3[t] = v;
    }
  }
}

// ---------------- prep 2: fold proj into V:  WVP_h = P_h @ Wv_h  (fp32), swizzled bf16 ----------------
__global__ void prep2_kernel(const float* __restrict__ qkv_w,
                             const float* __restrict__ qkv_b,
                             const float* __restrict__ proj_w,
                             const float* __restrict__ proj_b,
                             unsigned short* __restrict__ w_swz,
                             float* __restrict__ cb)
{
  int idx = blockIdx.x * 256 + threadIdx.x;
  if (idx < 82944) {
    int f = idx >> 9, r = idx & 511;
    int l = r >> 3, j = r & 7;
    int hn = f / 9, ks = f - hn * 9;
    int h = hn / 6, ntd = hn - h * 6;
    int d = ntd * 16 + (l & 15);
    int k = ks * 32 + ((l >> 4) << 3) + j;
    const float* pr = proj_w + d * 288 + h * 96;
    const float* wr = qkv_w + (size_t)(576 + h * 96) * 288 + k;
    float s = 0.f;
    #pragma unroll 8
    for (int t = 0; t < 96; ++t) s += pr[t] * wr[(size_t)t * 288];
    w_swz[165888 + idx] = f2bf(s);
  } else if (idx < 82944 + 96) {
    int d = idx - 82944;
    float s = proj_b[d];
    #pragma unroll 1
    for (int h = 0; h < 3; ++h) {
      const float* pr = proj_w + d * 288 + h * 96;
      const float* bv = qkv_b + 576 + h * 96;
      #pragma unroll 8
      for (int t = 0; t < 96; ++t) s += pr[t] * bv[t];
    }
    cb[d] = s;
  }
}

// ---------------- fused window attention, 8 waves, swizzled LDS, proj folded ----------------
#define A_OFF 0
#define Q_OFF 18432
#define K_OFF 23136
#define VT_OFF 27840
#define P_OFF 33984
#define SMEM_TOT 38080   // 76160 bytes -> 2 blocks/CU

__global__ __launch_bounds__(512, 4)
void wattn_kernel(const float* __restrict__ x, const float* __restrict__ y,
                  const float* __restrict__ z,
                  const float* __restrict__ qkv_b, const float* __restrict__ cb,
                  const unsigned short* __restrict__ w_swz,
                  const float* __restrict__ bm3,
                  float* __restrict__ out, int nW)
{
  __shared__ unsigned short smem[SMEM_TOT];
  const int b = blockIdx.x;
  const int tid = threadIdx.x;
  const int w = tid >> 6;        // 0..7
  const int lane = tid & 63;
  const int g = lane >> 4;
  const int cl = lane & 15;
  const int widx = b % nW;
  const int t4 = w & 3;          // row-tile for S/PV
  const int hf = w >> 2;         // half split

  // per-thread affine swizzle constants (reads)
  const int gx = ((g ^ ((cl >> 1) & 3)) << 3);   // A/Q/K granule adj (shorts)
  const int c2 = (cl >> 2) & 1;
  const int gv = ((g ^ (cl & 3)) << 3);          // Vt/P granule adj (shorts)
  const int s0 = c2 << 5;                        // Vt/P ks=0 offset (shorts)
  const int s1 = 32 - s0;                        // Vt/P ks=1 offset

  // ---- stage concat(x,y,z) -> LDS bf16, swizzled; all 9 loads in flight ----
  {
    const int row = tid >> 3;
    const int t7 = tid & 7;
    const int lb = row * 288 + (((t7 >> 1) ^ ((row >> 1) & 3)) << 3) + (t7 & 1) * 4;
    const size_t gb = ((size_t)b * NTOK + row) * 96 + t7 * 4;
    float4 v[9];
    if (row < NTOK) {
      #pragma unroll
      for (int k3 = 0; k3 < 3; ++k3) {
        v[0 + k3] = *(const float4*)(x + gb + k3 * 32);
        v[3 + k3] = *(const float4*)(y + gb + k3 * 32);
        v[6 + k3] = *(const float4*)(z + gb + k3 * 32);
      }
    } else {
      #pragma unroll
      for (int i = 0; i < 9; ++i) v[i] = make_float4(0.f, 0.f, 0.f, 0.f);
    }
    #pragma unroll
    for (int i = 0; i < 9; ++i) {
      uint2 d;
      d.x = pk2bf(v[i].x, v[i].y);
      d.y = pk2bf(v[i].z, v[i].w);
      *(uint2*)&smem[lb + (i / 3) * 96 + (i % 3) * 32] = d;
    }
  }

  // QKV pass-1 tile constants (tiles 0..15): wave owns 2w, 2w+1 (same type s per wave)
  const int tA = 2 * w;
  const int sA = (tA >= 12) ? 2 : ((tA >= 6) ? 1 : 0);
  const int dA = tA - 6 * sA, dB = dA + 1;
  // pass-2: all-V tiles 16,17 split by m-tile across 8 waves
  const int mw = w & 3;
  const int d2t = 4 + (w >> 2);

  f32x4 outacc[3];
  #pragma unroll
  for (int i = 0; i < 3; ++i) outacc[i] = f32x4{0.f, 0.f, 0.f, 0.f};

  __syncthreads();

  #pragma unroll 1
  for (int h = 0; h < 3; ++h) {
    __syncthreads();

    // ---- QKV pass 1: two tiles per wave, SEQUENTIAL, 1-deep weight prefetch, unroll 4 ----
    {
      const unsigned short* abase = &smem[A_OFF + cl * 288 + gx];
      if (sA == 2) {
        // V' waves: D rows=tokens, packed Vt writeback
        #pragma unroll 1
        for (int t = 0; t < 2; ++t) {
          const int ntd = t ? dB : dA;
          const unsigned short* wp = w_swz + (size_t)(2 * 18 + h * 6 + ntd) * 9 * 512 + lane * 8;
          f32x4 acc[4];
          #pragma unroll
          for (int m = 0; m < 4; ++m) acc[m] = f32x4{0.f, 0.f, 0.f, 0.f};
          short8 bf = *(const short8*)(wp);
          #pragma unroll 4
          for (int ks = 0; ks < 8; ++ks) {
            short8 bfn = *(const short8*)(wp + (ks + 1) * 512);
            short8 af0 = *(const short8*)(abase + 0 * (16 * 288) + ks * 32);
            short8 af1 = *(const short8*)(abase + 1 * (16 * 288) + ks * 32);
            short8 af2 = *(const short8*)(abase + 2 * (16 * 288) + ks * 32);
            short8 af3 = *(const short8*)(abase + 3 * (16 * 288) + ks * 32);
            __builtin_amdgcn_s_setprio(1);
            acc[0] = __builtin_amdgcn_mfma_f32_16x16x32_bf16(af0, bf, acc[0], 0, 0, 0);
            acc[1] = __builtin_amdgcn_mfma_f32_16x16x32_bf16(af1, bf, acc[1], 0, 0, 0);
            acc[2] = __builtin_amdgcn_mfma_f32_16x16x32_bf16(af2, bf, acc[2], 0, 0, 0);
            acc[3] = __builtin_amdgcn_mfma_f32_16x16x32_bf16(af3, bf, acc[3], 0, 0, 0);
            __builtin_amdgcn_s_setprio(0);
            bf = bfn;
          }
          {
            short8 af0 = *(const short8*)(abase + 0 * (16 * 288) + 8 * 32);
            short8 af1 = *(const short8*)(abase + 1 * (16 * 288) + 8 * 32);
            short8 af2 = *(const short8*)(abase + 2 * (16 * 288) + 8 * 32);
            short8 af3 = *(const short8*)(abase + 3 * (16 * 288) + 8 * 32);
            __builtin_amdgcn_s_setprio(1);
            acc[0] = __builtin_amdgcn_mfma_f32_16x16x32_bf16(af0, bf, acc[0], 0, 0, 0);
            acc[1] = __builtin_amdgcn_mfma_f32_16x16x32_bf16(af1, bf, acc[1], 0, 0, 0);
            acc[2] = __builtin_amdgcn_mfma_f32_16x16x32_bf16(af2, bf, acc[2], 0, 0, 0);
            acc[3] = __builtin_amdgcn_mfma_f32_16x16x32_bf16(af3, bf, acc[3], 0, 0, 0);
            __builtin_amdgcn_s_setprio(0);
          }
          #pragma unroll
          for (int m = 0; m < 4; ++m) {
            uint2 d;
            d.x = pk2bf(acc[m][0], acc[m][1]);
            d.y = pk2bf(acc[m][2], acc[m][3]);
            *(uint2*)&smem[VT_OFF + vp_ix(ntd * 16 + cl, m * 16 + (g << 2))] = d;
          }
        }
      } else {
        // Q/K waves: SWAPPED (D rows=d, cols=tokens), packed writeback, scale pre-folded
        const int s = sA;
        const int off = s ? K_OFF : Q_OFF;
        const float bsc = s ? 1.f : (QSC * LOG2E);
        #pragma unroll 1
        for (int t = 0; t < 2; ++t) {
          const int ntd = t ? dB : dA;
          const unsigned short* wp = w_swz + (size_t)(s * 18 + h * 6 + ntd) * 9 * 512 + lane * 8;
          f32x4 acc[4];
          #pragma unroll
          for (int m = 0; m < 4; ++m) acc[m] = f32x4{0.f, 0.f, 0.f, 0.f};
          short8 bf = *(const short8*)(wp);
          #pragma unroll 4
          for (int ks = 0; ks < 8; ++ks) {
            short8 bfn = *(const short8*)(wp + (ks + 1) * 512);
            short8 af0 = *(const short8*)(abase + 0 * (16 * 288) + ks * 32);
            short8 af1 = *(const short8*)(abase + 1 * (16 * 288) + ks * 32);
            short8 af2 = *(const short8*)(abase + 2 * (16 * 288) + ks * 32);
            short8 af3 = *(const short8*)(abase + 3 * (16 * 288) + ks * 32);
            __builtin_amdgcn_s_setprio(1);
            acc[0] = __builtin_amdgcn_mfma_f32_16x16x32_bf16(bf, af0, acc[0], 0, 0, 0);
            acc[1] = __builtin_amdgcn_mfma_f32_16x16x32_bf16(bf, af1, acc[1], 0, 0, 0);
            acc[2] = __builtin_amdgcn_mfma_f32_16x16x32_bf16(bf, af2, acc[2], 0, 0, 0);
            acc[3] = __builtin_amdgcn_mfma_f32_16x16x32_bf16(bf, af3, acc[3], 0, 0, 0);
            __builtin_amdgcn_s_setprio(0);
            bf = bfn;
          }
          {
            short8 af0 = *(const short8*)(abase + 0 * (16 * 288) + 8 * 32);
            short8 af1 = *(const short8*)(abase + 1 * (16 * 288) + 8 * 32);
            short8 af2 = *(const short8*)(abase + 2 * (16 * 288) + 8 * 32);
            short8 af3 = *(const short8*)(abase + 3 * (16 * 288) + 8 * 32);
            __builtin_amdgcn_s_setprio(1);
            acc[0] = __builtin_amdgcn_mfma_f32_16x16x32_bf16(bf, af0, acc[0], 0, 0, 0);
            acc[1] = __builtin_amdgcn_mfma_f32_16x16x32_bf16(bf, af1, acc[1], 0, 0, 0);
            acc[2] = __builtin_amdgcn_mfma_f32_16x16x32_bf16(bf, af2, acc[2], 0, 0, 0);
            acc[3] = __builtin_amdgcn_mfma_f32_16x16x32_bf16(bf, af3, acc[3], 0, 0, 0);
            __builtin_amdgcn_s_setprio(0);
          }
          const int d0 = ntd * 16 + (g << 2);
          float4 bq4 = *(const float4*)&qkv_b[s * 288 + h * 96 + d0];
          bq4.x *= bsc; bq4.y *= bsc; bq4.z *= bsc; bq4.w *= bsc;
          #pragma unroll
          for (int m = 0; m < 4; ++m) {
            int token = m * 16 + cl;
            uint2 dd;
            dd.x = pk2bf(acc[m][0] + bq4.x, acc[m][1] + bq4.y);
            dd.y = pk2bf(acc[m][2] + bq4.z, acc[m][3] + bq4.w);
            if (token < NTOK) {
              int gi = (d0 >> 3) ^ ((token >> 1) & 3);
              *(uint2*)&smem[off + token * 96 + (gi << 3) + (d0 & 7)] = dd;
            }
          }
        }
      }
    }

    // ---- QKV pass 2: V' tiles 16,17, one m-tile per wave, prefetched, unroll 4 ----
    {
      f32x4 acc2 = f32x4{0, 0, 0, 0};
      const unsigned short* wpC = w_swz + (size_t)(36 + h * 6 + d2t) * 9 * 512 + lane * 8;
      const unsigned short* abase2 = &smem[A_OFF + (mw * 16 + cl) * 288 + gx];
      short8 bf = *(const short8*)(wpC);
      #pragma unroll 4
      for (int ks = 0; ks < 8; ++ks) {
        short8 bfn = *(const short8*)(wpC + (ks + 1) * 512);
        short8 af = *(const short8*)(abase2 + ks * 32);
        acc2 = __builtin_amdgcn_mfma_f32_16x16x32_bf16(af, bf, acc2, 0, 0, 0);
        bf = bfn;
      }
      {
        short8 af = *(const short8*)(abase2 + 8 * 32);
        acc2 = __builtin_amdgcn_mfma_f32_16x16x32_bf16(af, bf, acc2, 0, 0, 0);
      }
      uint2 d;
      d.x = pk2bf(acc2[0], acc2[1]);
      d.y = pk2bf(acc2[2], acc2[3]);
      *(uint2*)&smem[VT_OFF + vp_ix(d2t * 16 + cl, mw * 16 + (g << 2))] = d;
    }
    __syncthreads();

    // ---- prefetch combined bias+mask (padded stride 64, log2 domain) ----
    float bm[2][4];
    {
      const float* bmb = bm3 + ((size_t)(h * nW + widx)) * (49 * 64) + cl;
      #pragma unroll
      for (int rr = 0; rr < 2; ++rr) {
        int n = t4 * 16 + (g << 2) + 2 * hf + rr;
        int nn = n < NTOK ? n : NTOK - 1;
        const float* brow = bmb + nn * 64;
        #pragma unroll
        for (int nt = 0; nt < 4; ++nt) bm[rr][nt] = brow[nt * 16];
      }
    }

    // ---- S = Q K^T (wave-pair duplicates its row-tile) ----
    f32x4 sacc[4];
    #pragma unroll
    for (int nt = 0; nt < 4; ++nt) sacc[nt] = f32x4{0.f, 0.f, 0.f, 0.f};
    {
      const unsigned short* qbase = &smem[Q_OFF + (t4 * 16 + cl) * 96 + gx];
      const unsigned short* kbase = &smem[K_OFF + cl * 96 + gx];
      #pragma unroll 1
      for (int ks = 0; ks < 3; ++ks) {
        short8 aq = *(const short8*)(qbase + ks * 32);
        short8 bk0 = *(const short8*)(kbase + 0 * (16 * 96) + ks * 32);
        short8 bk1 = *(const short8*)(kbase + 1 * (16 * 96) + ks * 32);
        short8 bk2 = *(const short8*)(kbase + 2 * (16 * 96) + ks * 32);
        short8 bk3 = *(const short8*)(kbase + 3 * (16 * 96) + ks * 32);
        __builtin_amdgcn_s_setprio(1);
        sacc[0] = __builtin_amdgcn_mfma_f32_16x16x32_bf16(aq, bk0, sacc[0], 0, 0, 0);
        sacc[1] = __builtin_amdgcn_mfma_f32_16x16x32_bf16(aq, bk1, sacc[1], 0, 0, 0);
        sacc[2] = __builtin_amdgcn_mfma_f32_16x16x32_bf16(aq, bk2, sacc[2], 0, 0, 0);
        sacc[3] = __builtin_amdgcn_mfma_f32_16x16x32_bf16(aq, bk3, sacc[3], 0, 0, 0);
        __builtin_amdgcn_s_setprio(0);
      }
    }

    // ---- softmax (log2 domain): wave handles rows r in {2hf, 2hf+1} ----
    #pragma unroll
    for (int r = 0; r < 4; ++r) {
      if ((r >> 1) != hf) continue;     // uniform; r compile-time
      const int rr = r & 1;
      int n = t4 * 16 + (g << 2) + r;
      float vals[4];
      #pragma unroll
      for (int nt = 0; nt < 4; ++nt) vals[nt] = sacc[nt][r] + bm[rr][nt];
      float mx = fmaxf(fmaxf(vals[0], vals[1]), fmaxf(vals[2], vals[3]));
      mx = fmaxf(mx, __shfl_xor(mx, 1));
      mx = fmaxf(mx, __shfl_xor(mx, 2));
      mx = fmaxf(mx, __shfl_xor(mx, 4));
      mx = fmaxf(mx, __shfl_xor(mx, 8));
      float sum = 0.f;
      #pragma unroll
      for (int nt = 0; nt < 4; ++nt) {
        float e = __builtin_amdgcn_exp2f(vals[nt] - mx);
        vals[nt] = e;
        sum += e;
      }
      sum += __shfl_xor(sum, 1);
      sum += __shfl_xor(sum, 2);
      sum += __shfl_xor(sum, 4);
      sum += __shfl_xor(sum, 8);
      float inv = __builtin_amdgcn_rcpf(sum);
      unsigned d01 = pk2bf(vals[0] * inv, vals[1] * inv);
      unsigned d23 = pk2bf(vals[2] * inv, vals[3] * inv);
      smem[P_OFF + vp_ix(n, 0 * 16 + cl)] = (unsigned short)d01;
      smem[P_OFF + vp_ix(n, 1 * 16 + cl)] = (unsigned short)(d01 >> 16);
      smem[P_OFF + vp_ix(n, 2 * 16 + cl)] = (unsigned short)d23;
      smem[P_OFF + vp_ix(n, 3 * 16 + cl)] = (unsigned short)(d23 >> 16);
    }
    __syncthreads();

    // ---- out partial: outacc += (P @ V') SWAPPED -> D rows=d, cols=tokens ----
    {
      const unsigned short* pbase = &smem[P_OFF + (t4 * 16 + cl) * 64 + gv];
      const unsigned short* vbase = &smem[VT_OFF + (hf * 3 * 16 + cl) * 64 + gv];
      #pragma unroll
      for (int ks = 0; ks < 2; ++ks) {
        const int ko = ks ? s1 : s0;
        short8 ap = *(const short8*)(pbase + ko);
        short8 bv0 = *(const short8*)(vbase + 0 * (16 * 64) + ko);
        short8 bv1 = *(const short8*)(vbase + 1 * (16 * 64) + ko);
        short8 bv2 = *(const short8*)(vbase + 2 * (16 * 64) + ko);
        __builtin_amdgcn_s_setprio(1);
        outacc[0] = __builtin_amdgcn_mfma_f32_16x16x32_bf16(bv0, ap, outacc[0], 0, 0, 0);
        outacc[1] = __builtin_amdgcn_mfma_f32_16x16x32_bf16(bv1, ap, outacc[1], 0, 0, 0);
        outacc[2] = __builtin_amdgcn_mfma_f32_16x16x32_bf16(bv2, ap, outacc[2], 0, 0, 0);
        __builtin_amdgcn_s_setprio(0);
      }
    }
  }

  // ---- epilogue: thread holds d = (hf*3+jj)*16+g*4+r at token n = t4*16+cl ----
  {
    int n = t4 * 16 + cl;
    if (n < NTOK) {
      size_t ob = ((size_t)b * NTOK + n) * 96;
      #pragma unroll
      for (int jj = 0; jj < 3; ++jj) {
        int d0 = (hf * 3 + jj) * 16 + (g << 2);
        float4 c4 = *(const float4*)&cb[d0];
        float4 o;
        o.x = outacc[jj][0] + c4.x;
        o.y = outacc[jj][1] + c4.y;
        o.z = outacc[jj][2] + c4.z;
        o.w = outacc[jj][3] + c4.w;
        *(float4*)&out[ob + d0] = o;
      }
    }
  }
}

extern "C" void kernel_launch(void* const* d_in, const int* in_sizes, int n_in,
                              void* d_out, int out_size, void* d_ws, size_t ws_size,
                              hipStream_t stream) {
  const float* x          = (const float*)d_in[0];
  const float* y          = (const float*)d_in[1];
  const float* z          = (const float*)d_in[2];
  const float* mask       = (const float*)d_in[3];
  const float* qkv_w      = (const float*)d_in[4];
  const float* qkv_b      = (const float*)d_in[5];
  const float* proj_w     = (const float*)d_in[6];
  const float* proj_b     = (const float*)d_in[7];
  const float* bias_table = (const float*)d_in[8];
  const int*   rel_index  = (const int*)d_in[9];

  int B  = in_sizes[0] / (NTOK * 96);
  int nW = in_sizes[3] / (NTOK * NTOK);

  unsigned short* w_swz = (unsigned short*)d_ws;        // 248832 shorts (54 tiles)
  float*          bm3   = (float*)(w_swz + 248832);     // 3*nW*49*64 floats
  float*          cbv   = bm3 + (size_t)3 * nW * 49 * 64;  // 96 floats

  int prep1_elems = 165888 + 3 * nW * 49 * 64;
  prep_kernel<<<(prep1_elems + 255) / 256, 256, 0, stream>>>(
      qkv_w, bias_table, rel_index, mask, w_swz, bm3, nW);
  prep2_kernel<<<325, 256, 0, stream>>>(qkv_w, qkv_b, proj_w, proj_b, w_swz, cbv);
  wattn_kernel<<<B, 512, 0, stream>>>(x, y, z, qkv_b, cbv,
                                      w_swz, bm3, (float*)d_out, nW);
}